// Round 1
// baseline (56.077 us; speedup 1.0000x reference)
//
#include <hip/hip_runtime.h>

// out = (up_h(a) + up_w(b)) / 2
// a: (N, Ha, Wo) upsampled along H -> (N, 2*Ha, Wo)
// b: (N, H2, Wb) upsampled along W -> (N, H2, 2*Wb) ; H2 = 2*Ha, Wo = 2*Wb
// Upsample closed form (L=5, s=2), output length 2W from input length W:
//   j odd , j<=2W-3 : (x[(j-1)/2] + x[(j+1)/2]) / 2
//   j even interior : (x[j/2-1] + x[j/2] + x[j/2+1]) / 3
//   j==0            : (x[0] + x[1]) / 2
//   j==2W-2         : (x[W-2] + x[W-1]) / 2
//   j==2W-1         : x[W-1]

__device__ __forceinline__ float4 f4_add(float4 p, float4 q) {
    return make_float4(p.x + q.x, p.y + q.y, p.z + q.z, p.w + q.w);
}
__device__ __forceinline__ float4 f4_scale(float4 p, float s) {
    return make_float4(p.x * s, p.y * s, p.z * s, p.w * s);
}

template <int Ha, int Wo, int Wb>
__global__ __launch_bounds__(256) void up_combine_kernel(
    const float* __restrict__ a,  // (N, Ha, Wo)
    const float* __restrict__ b,  // (N, 2*Ha, Wb)
    float* __restrict__ out,      // (N, 2*Ha, Wo)
    int N)
{
    constexpr int H2 = 2 * Ha;
    constexpr int T  = Wo / 4;   // float4 slots per output row
    constexpr float THIRD = 1.0f / 3.0f;

    const int idx = blockIdx.x * blockDim.x + threadIdx.x;
    const int total = N * H2 * T;
    if (idx >= total) return;

    const int t  = idx % T;
    const int h2 = (idx / T) % H2;
    const int n  = idx / (T * H2);

    // ---------------- up_h(a) at (n, h2, 4t..4t+3) ----------------
    const float4* a4 = reinterpret_cast<const float4*>(a) + (size_t)n * Ha * T;
    float4 vh;
    const int h = h2 >> 1;
    if (h2 & 1) {
        if (h2 == H2 - 1) {
            vh = a4[(size_t)(Ha - 1) * T + t];
        } else {
            float4 r0 = a4[(size_t)h * T + t];
            float4 r1 = a4[(size_t)(h + 1) * T + t];
            vh = f4_scale(f4_add(r0, r1), 0.5f);
        }
    } else {
        if (h2 == 0) {
            float4 r0 = a4[t];
            float4 r1 = a4[T + t];
            vh = f4_scale(f4_add(r0, r1), 0.5f);
        } else if (h2 == H2 - 2) {
            float4 r0 = a4[(size_t)(Ha - 2) * T + t];
            float4 r1 = a4[(size_t)(Ha - 1) * T + t];
            vh = f4_scale(f4_add(r0, r1), 0.5f);
        } else {
            float4 rm = a4[(size_t)(h - 1) * T + t];
            float4 r0 = a4[(size_t)h * T + t];
            float4 rp = a4[(size_t)(h + 1) * T + t];
            vh = f4_scale(f4_add(f4_add(rm, r0), rp), THIRD);
        }
    }

    // ---------------- up_w(b) at (n, h2, 4t..4t+3) ----------------
    // outputs w = 4t..4t+3 need b[2t-1 .. 2t+2]
    const float* brow = b + ((size_t)n * H2 + h2) * Wb;
    const int ww = 2 * t;
    const float b0 = brow[ww];
    const float b1 = brow[ww + 1];
    const float bm = (t > 0)     ? brow[ww - 1] : 0.0f;
    const float b2 = (t < T - 1) ? brow[ww + 2] : 0.0f;

    float4 vw;
    // w = 4t (even): interior (bm+b0+b1)/3 ; w==0 -> (b0+b1)/2
    vw.x = (t > 0) ? (bm + b0 + b1) * THIRD : 0.5f * (b0 + b1);
    // w = 4t+1 (odd, never last): (b0+b1)/2
    vw.y = 0.5f * (b0 + b1);
    // w = 4t+2 (even): interior (b0+b1+b2)/3 ; w==Wo-2 -> (b0+b1)/2
    vw.z = (t < T - 1) ? (b0 + b1 + b2) * THIRD : 0.5f * (b0 + b1);
    // w = 4t+3 (odd): interior (b1+b2)/2 ; w==Wo-1 -> b1
    vw.w = (t < T - 1) ? 0.5f * (b1 + b2) : b1;

    // ---------------- combine & store ----------------
    float4 res = f4_scale(f4_add(vh, vw), 0.5f);
    float4* o4 = reinterpret_cast<float4*>(out) + ((size_t)n * H2 + h2) * T + t;
    *o4 = res;
}

extern "C" void kernel_launch(void* const* d_in, const int* in_sizes, int n_in,
                              void* d_out, int out_size, void* d_ws, size_t ws_size,
                              hipStream_t stream) {
    const float* x0 = (const float*)d_in[0];  // (8,64, 64,256)
    const float* x1 = (const float*)d_in[1];  // (8,64,128,128)
    const float* x2 = (const float*)d_in[2];  // (8,64,256, 64)
    float* out = (float*)d_out;

    const int N = 8 * 64;  // 512 (batch*channels collapsed)

    // out0 = (up_h(x0) + up_w(x1)) / 2 : (N,128,256)
    float* out0 = out;
    // out1 = (up_h(x1) + up_w(x2)) / 2 : (N,256,128)
    float* out1 = out + (size_t)N * 128 * 256;

    {
        constexpr int Ha = 64, Wo = 256, Wb = 128;
        const int total = N * (2 * Ha) * (Wo / 4);
        dim3 grid((total + 255) / 256), block(256);
        hipLaunchKernelGGL((up_combine_kernel<Ha, Wo, Wb>), grid, block, 0, stream,
                           x0, x1, out0, N);
    }
    {
        constexpr int Ha = 128, Wo = 128, Wb = 64;
        const int total = N * (2 * Ha) * (Wo / 4);
        dim3 grid((total + 255) / 256), block(256);
        hipLaunchKernelGGL((up_combine_kernel<Ha, Wo, Wb>), grid, block, 0, stream,
                           x1, x2, out1, N);
    }
}

// Round 2
// 46.915 us; speedup vs baseline: 1.1953x; 1.1953x over previous
//
#include <hip/hip_runtime.h>

// Fused anisotropic upsampling:
//   out0 = (up_h(x0) + up_w(x1)) / 2 : (N,128,256), N = 8*64 = 512
//   out1 = (up_h(x1) + up_w(x2)) / 2 : (N,256,128)
// Upsample closed form (L=5, s=2), output length 2W from input length W:
//   j odd , j<=2W-3 : (x[(j-1)/2] + x[(j+1)/2]) / 2
//   j even interior : (x[j/2-1] + x[j/2] + x[j/2+1]) / 3
//   j==0            : (x[0] + x[1]) / 2
//   j==2W-2         : (x[W-2] + x[W-1]) / 2
//   j==2W-1         : x[W-1]
//
// Each thread produces a 2x8 output tile: rows h2=2h and 2h+1, cols 8t..8t+7.
// The three a-rows (h-1,h,h+1) are loaded once and reused for both output rows.

__device__ __forceinline__ float4 f4_add(float4 p, float4 q) {
    return make_float4(p.x + q.x, p.y + q.y, p.z + q.z, p.w + q.w);
}
__device__ __forceinline__ float4 f4_scale(float4 p, float s) {
    return make_float4(p.x * s, p.y * s, p.z * s, p.w * s);
}

// up_w of one b-row segment: inputs b[4t-1..4t+4] -> outputs w=8t..8t+7 (two float4)
__device__ __forceinline__ void upw8(float bm, float4 bq, float bp,
                                     bool first, bool last,
                                     float4& lo, float4& hi) {
    constexpr float THIRD = 1.0f / 3.0f;
    lo.x = first ? 0.5f * (bq.x + bq.y) : (bm + bq.x + bq.y) * THIRD;
    lo.y = 0.5f * (bq.x + bq.y);
    lo.z = (bq.x + bq.y + bq.z) * THIRD;
    lo.w = 0.5f * (bq.y + bq.z);
    hi.x = (bq.y + bq.z + bq.w) * THIRD;
    hi.y = 0.5f * (bq.z + bq.w);
    hi.z = last ? 0.5f * (bq.z + bq.w) : (bq.z + bq.w + bp) * THIRD;
    hi.w = last ? bq.w : 0.5f * (bq.w + bp);
}

template <int Ha, int Wo>
__device__ __forceinline__ void up_combine_body(
    const float* __restrict__ a,   // (N, Ha, Wo)
    const float* __restrict__ b,   // (N, 2*Ha, Wo/2)
    float* __restrict__ out,       // (N, 2*Ha, Wo)
    int lin)                       // linear thread id within this segment
{
    constexpr int H2 = 2 * Ha;
    constexpr int Wb = Wo / 2;
    constexpr int T8 = Wo / 8;     // 8-wide groups per output row
    constexpr float THIRD = 1.0f / 3.0f;

    const int t = lin % T8;
    const int h = (lin / T8) % Ha;
    const int n = lin / (T8 * Ha);

    // ---------------- a rows (as 2x float4 each) ----------------
    const float4* a4 = reinterpret_cast<const float4*>(a) + (size_t)n * Ha * (Wo / 4);
    const int c4 = 2 * t;  // float4 column
    float4 a0l = a4[(size_t)h * (Wo / 4) + c4];
    float4 a0h = a4[(size_t)h * (Wo / 4) + c4 + 1];
    float4 aml, amh, apl, aph;
    if (h > 0) {
        aml = a4[(size_t)(h - 1) * (Wo / 4) + c4];
        amh = a4[(size_t)(h - 1) * (Wo / 4) + c4 + 1];
    }
    if (h < Ha - 1) {
        apl = a4[(size_t)(h + 1) * (Wo / 4) + c4];
        aph = a4[(size_t)(h + 1) * (Wo / 4) + c4 + 1];
    }

    // up_h even row (h2 = 2h) and odd row (h2 = 2h+1)
    float4 evl, evh, odl, odh;
    if (h == 0) {
        evl = f4_scale(f4_add(a0l, apl), 0.5f);
        evh = f4_scale(f4_add(a0h, aph), 0.5f);
    } else if (h == Ha - 1) {
        evl = f4_scale(f4_add(aml, a0l), 0.5f);
        evh = f4_scale(f4_add(amh, a0h), 0.5f);
    } else {
        evl = f4_scale(f4_add(f4_add(aml, a0l), apl), THIRD);
        evh = f4_scale(f4_add(f4_add(amh, a0h), aph), THIRD);
    }
    if (h == Ha - 1) {
        odl = a0l; odh = a0h;
    } else {
        odl = f4_scale(f4_add(a0l, apl), 0.5f);
        odh = f4_scale(f4_add(a0h, aph), 0.5f);
    }

    // ---------------- b rows: h2 = 2h and 2h+1 ----------------
    const bool first = (t == 0), last = (t == T8 - 1);
    const float* brow0 = b + ((size_t)n * H2 + 2 * h) * Wb;
    const float* brow1 = brow0 + Wb;

    float4 bq0 = *reinterpret_cast<const float4*>(brow0 + 4 * t);
    float4 bq1 = *reinterpret_cast<const float4*>(brow1 + 4 * t);
    float bm0 = first ? 0.0f : brow0[4 * t - 1];
    float bm1 = first ? 0.0f : brow1[4 * t - 1];
    float bp0 = last ? 0.0f : brow0[4 * t + 4];
    float bp1 = last ? 0.0f : brow1[4 * t + 4];

    float4 w0l, w0h, w1l, w1h;
    upw8(bm0, bq0, bp0, first, last, w0l, w0h);
    upw8(bm1, bq1, bp1, first, last, w1l, w1h);

    // ---------------- combine & store ----------------
    float4* o4 = reinterpret_cast<float4*>(out) + ((size_t)n * H2 + 2 * h) * (Wo / 4) + c4;
    o4[0]          = f4_scale(f4_add(evl, w0l), 0.5f);
    o4[1]          = f4_scale(f4_add(evh, w0h), 0.5f);
    o4[Wo / 4]     = f4_scale(f4_add(odl, w1l), 0.5f);
    o4[Wo / 4 + 1] = f4_scale(f4_add(odh, w1h), 0.5f);
}

__global__ __launch_bounds__(256) void fused_up_kernel(
    const float* __restrict__ x0,
    const float* __restrict__ x1,
    const float* __restrict__ x2,
    float* __restrict__ out0,
    float* __restrict__ out1,
    int g0_blocks)
{
    if (blockIdx.x < (unsigned)g0_blocks) {
        const int lin = blockIdx.x * blockDim.x + threadIdx.x;
        up_combine_body<64, 256>(x0, x1, out0, lin);
    } else {
        const int lin = (blockIdx.x - g0_blocks) * blockDim.x + threadIdx.x;
        up_combine_body<128, 128>(x1, x2, out1, lin);
    }
}

extern "C" void kernel_launch(void* const* d_in, const int* in_sizes, int n_in,
                              void* d_out, int out_size, void* d_ws, size_t ws_size,
                              hipStream_t stream) {
    const float* x0 = (const float*)d_in[0];  // (8,64, 64,256)
    const float* x1 = (const float*)d_in[1];  // (8,64,128,128)
    const float* x2 = (const float*)d_in[2];  // (8,64,256, 64)
    float* out = (float*)d_out;

    const int N = 8 * 64;  // 512
    float* out0 = out;
    float* out1 = out + (size_t)N * 128 * 256;

    // Segment 0: N*Ha*T8 = 512*64*32 = 1,048,576 threads -> 4096 blocks
    // Segment 1: 512*128*16 = 1,048,576 threads -> 4096 blocks
    const int g0 = (N * 64 * (256 / 8)) / 256;
    const int g1 = (N * 128 * (128 / 8)) / 256;
    dim3 grid(g0 + g1), block(256);
    hipLaunchKernelGGL(fused_up_kernel, grid, block, 0, stream,
                       x0, x1, x2, out0, out1, g0);
}